// Round 7
// baseline (371.444 us; speedup 1.0000x reference)
//
#include <hip/hip_runtime.h>

typedef __attribute__((ext_vector_type(8))) short short8;
typedef __attribute__((ext_vector_type(4))) float f32x4;
typedef __attribute__((ext_vector_type(4))) int i32x4;
typedef __attribute__((ext_vector_type(4))) unsigned short u16x4;
typedef __attribute__((ext_vector_type(8))) unsigned short u16x8;
typedef __attribute__((ext_vector_type(2))) unsigned int u32x2;

#define B_  4
#define N_  2048
#define D_  512
#define H_  8
#define DH_ 64
#define M_  (B_ * N_)   // 8192

__device__ __forceinline__ float bf2f(unsigned short s) {
    union { unsigned u; float f; } un; un.u = ((unsigned)s) << 16; return un.f;
}
__device__ __forceinline__ unsigned short f2bf(float f) {
    union { float f; unsigned u; } un; un.f = f;
    unsigned r = un.u + 0x7FFFu + ((un.u >> 16) & 1u);
    return (unsigned short)(r >> 16);
}
__device__ __forceinline__ unsigned packbf(float lo, float hi) {
    union { float f; unsigned u; } a, b;
    a.f = lo; b.f = hi;
    return __builtin_amdgcn_perm(b.u + 0x8000u, a.u + 0x8000u, 0x07060302u);
}
__device__ __forceinline__ float lo16f(unsigned u) {
    union { unsigned u; float f; } un; un.u = u << 16; return un.f;
}
__device__ __forceinline__ float hi16f(unsigned u) {
    union { unsigned u; float f; } un; un.u = u & 0xFFFF0000u; return un.f;
}

typedef __attribute__((address_space(1))) const void gvoid;
typedef __attribute__((address_space(3))) void svoid;
__device__ __forceinline__ void load16_lds(const void* g, void* s) {
    __builtin_amdgcn_global_load_lds((gvoid*)g, (svoid*)s, 16, 0, 0);
}

// ---------------------------------------------------------------------------
// fp32 -> bf16 conversions
// ---------------------------------------------------------------------------
__global__ __launch_bounds__(256) void cvt_x(const float* __restrict__ src,
                                             unsigned short* __restrict__ dst) {
    const int i = (blockIdx.x * 256 + threadIdx.x) * 4;
    f32x4 v = *(const f32x4*)(src + i);
    u16x4 o;
    o[0] = f2bf(v[0]); o[1] = f2bf(v[1]); o[2] = f2bf(v[2]); o[3] = f2bf(v[3]);
    *(u16x4*)(dst + i) = o;
}

__global__ __launch_bounds__(256) void cvt_bias(const float* __restrict__ src,
                                                unsigned short* __restrict__ dst) {
    const int i = (blockIdx.x * 256 + threadIdx.x) * 8;
    f32x4 v0 = *(const f32x4*)(src + i);
    f32x4 v1 = *(const f32x4*)(src + i + 4);
    u16x8 o;
    o[0] = f2bf(v0[0]); o[1] = f2bf(v0[1]); o[2] = f2bf(v0[2]); o[3] = f2bf(v0[3]);
    o[4] = f2bf(v1[0]); o[5] = f2bf(v1[1]); o[6] = f2bf(v1[2]); o[7] = f2bf(v1[3]);
    *(u16x8*)(dst + i) = o;
}

__global__ __launch_bounds__(256) void cvt_w(const float* __restrict__ W0,
                                             const float* __restrict__ W1,
                                             const float* __restrict__ W2,
                                             const float* __restrict__ W3,
                                             unsigned short* __restrict__ dst) {
    const int sel = blockIdx.y;
    const float* src = (sel == 0) ? W0 : (sel == 1) ? W1 : (sel == 2) ? W2 : W3;
    unsigned short* d = dst + (size_t)sel * D_ * D_;
    const int i = (blockIdx.x * 256 + threadIdx.x) * 4;
    f32x4 v = *(const f32x4*)(src + i);
    u16x4 o;
    o[0] = f2bf(v[0]); o[1] = f2bf(v[1]); o[2] = f2bf(v[2]); o[3] = f2bf(v[3]);
    *(u16x4*)(d + i) = o;
}

// ---------------------------------------------------------------------------
// NT GEMM with global_load_lds(16B) staging + XOR-swizzled LDS.
// Tile 128x128, BK=32, 4 waves; optional fused per-head LN.
// ---------------------------------------------------------------------------
template <bool F32OUT, bool LNF>
__global__ __launch_bounds__(256, 2) void gemm_nt(
    const unsigned short* __restrict__ A,
    const unsigned short* __restrict__ W,     // [nsel][512][512]
    const float* __restrict__ Bv0,
    const float* __restrict__ Bv1,
    const float* __restrict__ Bv2,
    const float* __restrict__ g0, const float* __restrict__ be0,
    const float* __restrict__ g1, const float* __restrict__ be1,
    unsigned short* __restrict__ outb,
    float* __restrict__ outf)
{
    const int mt = blockIdx.x;
    const int nt = blockIdx.y;
    const int sel = nt >> 2;
    const unsigned short* Wp = W + (size_t)sel * D_ * D_;
    const float* Bv = (sel == 0) ? Bv0 : (sel == 1) ? Bv1 : Bv2;
    const int n0 = (nt & 3) * 128;

    __shared__ __align__(16) unsigned short As[128 * 32];
    __shared__ __align__(16) unsigned short Bs[128 * 32];

    const int tid = threadIdx.x;
    const int w   = tid >> 6;
    const int l   = tid & 63;
    const int l15 = l & 15;
    const int qd  = l >> 4;
    const int wr  = w >> 1;
    const int wc  = w & 1;

    int srow[2], scol[2];
#pragma unroll
    for (int c = 0; c < 2; ++c) {
        const int g   = (w * 2 + c) * 64 + l;
        const int row = g >> 2;
        srow[c] = row;
        scol[c] = ((g & 3) ^ (row & 3)) * 8;
    }

    f32x4 acc[4][4];
#pragma unroll
    for (int i = 0; i < 4; ++i)
#pragma unroll
        for (int j = 0; j < 4; ++j)
            acc[i][j] = (f32x4){0.f, 0.f, 0.f, 0.f};

    const int swz = qd ^ (l15 & 3);

    for (int k0 = 0; k0 < D_; k0 += 32) {
        __syncthreads();
#pragma unroll
        for (int c = 0; c < 2; ++c) {
            load16_lds(A  + (size_t)(mt * 128 + srow[c]) * D_ + k0 + scol[c],
                       As + (w * 2 + c) * 512);
            load16_lds(Wp + (size_t)(n0 + srow[c]) * D_ + k0 + scol[c],
                       Bs + (w * 2 + c) * 512);
        }
        __syncthreads();

        short8 af[4], bfr[4];
#pragma unroll
        for (int rt = 0; rt < 4; ++rt)
            af[rt] = *(const short8*)&As[(wr * 64 + rt * 16 + l15) * 32 + swz * 8];
#pragma unroll
        for (int ct = 0; ct < 4; ++ct)
            bfr[ct] = *(const short8*)&Bs[(wc * 64 + ct * 16 + l15) * 32 + swz * 8];
#pragma unroll
        for (int rt = 0; rt < 4; ++rt)
#pragma unroll
            for (int ct = 0; ct < 4; ++ct)
                acc[rt][ct] = __builtin_amdgcn_mfma_f32_16x16x32_bf16(
                    af[rt], bfr[ct], acc[rt][ct], 0, 0, 0);
    }

    const float* gam = (sel == 0) ? g0 : g1;
    const float* bet = (sel == 0) ? be0 : be1;
    float gv[4], bv2[4];
    if (LNF) {
#pragma unroll
        for (int ct = 0; ct < 4; ++ct) { gv[ct] = gam[ct * 16 + l15]; bv2[ct] = bet[ct * 16 + l15]; }
    }

#pragma unroll
    for (int rt = 0; rt < 4; ++rt) {
        float v[4][4];
#pragma unroll
        for (int ct = 0; ct < 4; ++ct) {
            const float bias = Bv[n0 + wc * 64 + ct * 16 + l15];
#pragma unroll
            for (int r = 0; r < 4; ++r) v[ct][r] = acc[rt][ct][r] + bias;
        }
        if (LNF && sel < 2) {
#pragma unroll
            for (int r = 0; r < 4; ++r) {
                float s  = v[0][r] + v[1][r] + v[2][r] + v[3][r];
                float s2 = v[0][r]*v[0][r] + v[1][r]*v[1][r] + v[2][r]*v[2][r] + v[3][r]*v[3][r];
#pragma unroll
                for (int o = 1; o <= 8; o <<= 1) {
                    s  += __shfl_xor(s, o);
                    s2 += __shfl_xor(s2, o);
                }
                const float mu  = s * 0.015625f;
                const float var = s2 * 0.015625f - mu * mu;
                const float rs  = rsqrtf(var + 1e-6f);
#pragma unroll
                for (int ct = 0; ct < 4; ++ct)
                    v[ct][r] = (v[ct][r] - mu) * rs * gv[ct] + bv2[ct];
            }
        }
#pragma unroll
        for (int ct = 0; ct < 4; ++ct) {
            const int col  = n0 + wc * 64 + ct * 16 + l15;
            const int row0 = mt * 128 + wr * 64 + rt * 16 + qd * 4;
#pragma unroll
            for (int r = 0; r < 4; ++r) {
                const size_t oidx = (size_t)(row0 + r) * D_ + col;
                if (F32OUT) outf[oidx] = v[ct][r];
                else        outb[(size_t)sel * M_ * D_ + oidx] = f2bf(v[ct][r]);
            }
        }
    }
}

// ---------------------------------------------------------------------------
// V transpose: V[b*2048+n][dh512] -> Vt[b][dh512][n2048]
// ---------------------------------------------------------------------------
__global__ __launch_bounds__(256) void transpose_v(
    const unsigned short* __restrict__ V, unsigned short* __restrict__ Vt)
{
    const int nt = blockIdx.x;
    const int dt = blockIdx.y;
    const int b  = blockIdx.z;
    __shared__ __align__(16) unsigned short T[64][72];
    const int t = threadIdx.x;

#pragma unroll
    for (int half = 0; half < 2; ++half) {
        const int n = half * 32 + (t >> 3);
        const int c = (t & 7) * 8;
        short8 v = *(const short8*)(V + (size_t)(b * N_ + nt * 64 + n) * D_ + dt * 64 + c);
#pragma unroll
        for (int j = 0; j < 8; ++j) T[c + j][n] = (unsigned short)v[j];
    }
    __syncthreads();
    const int dh = t >> 2, p = t & 3;
    i32x4 a0 = *(const i32x4*)&T[dh][p * 16];
    i32x4 a1 = *(const i32x4*)&T[dh][p * 16 + 8];
    unsigned short* dst = Vt + ((size_t)b * D_ + dt * 64 + dh) * N_ + nt * 64 + p * 16;
    *(i32x4*)dst       = a0;
    *(i32x4*)(dst + 8) = a1;
}

// ---------------------------------------------------------------------------
// attn6: attn2 topology (block order = (hg,qt,b), 4 heads/block, 32 q-rows)
// but 512-thread blocks: waves 0-3 = heads x kv[0,1024), waves 4-7 = same
// heads x kv[1024,2048). 16 kv64-iters/wave, wave-private P LDS, no barriers
// in loop; one 2-way LDS merge at the end. Bias read as bf16 (pre-converted).
// ---------------------------------------------------------------------------
__global__ __launch_bounds__(512, 4) void attn6(
    const unsigned short* __restrict__ Qm,
    const unsigned short* __restrict__ Km,
    const unsigned short* __restrict__ Vt,
    const unsigned short* __restrict__ bias16,
    unsigned short* __restrict__ AO)
{
    const int hg = blockIdx.x;   // 0..1
    const int qt = blockIdx.y;   // 0..63
    const int b  = blockIdx.z;   // 0..3
    const int w  = threadIdx.x >> 6;       // 0..7
    const int h  = hg * 4 + (w & 3);
    const int s  = w >> 2;                 // kv split 0..1
    const int l  = threadIdx.x & 63;
    const int l15 = l & 15;
    const int qd  = l >> 4;
    const int q0 = qt * 32;

    // smem: Pw[8][32][72] bf16 (36864B) reused as Obuf[4][32][68] f32 (34816B)
    __shared__ __align__(16) unsigned char smem[36864 + 1024];
    unsigned short (*Pw)[32][72] = (unsigned short(*)[32][72])smem;
    float (*Obuf)[32][68] = (float(*)[32][68])smem;
    float* mlm = (float*)(smem + 36864);          // [4][32]
    float* mll = (float*)(smem + 36864 + 512);    // [4][32]

    // Q fragments (B-operand): n=q(ct*16+l15), k=dh(hf*32+qd*8+j)
    short8 qf[2][2];
#pragma unroll
    for (int ct = 0; ct < 2; ++ct)
#pragma unroll
        for (int hf = 0; hf < 2; ++hf)
            qf[ct][hf] = *(const short8*)(Qm +
                (size_t)(b * N_ + q0 + ct * 16 + l15) * D_ + h * DH_ + hf * 32 + qd * 8);

    f32x4 Ot[4][2];
#pragma unroll
    for (int rt = 0; rt < 4; ++rt)
#pragma unroll
        for (int ct = 0; ct < 2; ++ct) Ot[rt][ct] = (f32x4){0.f, 0.f, 0.f, 0.f};
    float m_i[2] = {-3.0e38f, -3.0e38f};
    float l_i[2] = {0.f, 0.f};   // lane-partial

    const unsigned short* kb_ = Km + (size_t)b * N_ * D_ + h * DH_;
    const unsigned short* vb_ = Vt + ((size_t)b * D_ + h * DH_) * N_;
    const unsigned short* bb_ = bias16 + (size_t)b * N_ * N_ + (size_t)q0 * N_;

    const int kvbase = s * 1024;

    for (int kt = 0; kt < 16; ++kt) {
        const int kv0 = kvbase + kt * 64;

        // K fragments (A-operand): m=kv(rt*16+l15), k=dh
        short8 kf[4][2];
#pragma unroll
        for (int rt = 0; rt < 4; ++rt)
#pragma unroll
            for (int hf = 0; hf < 2; ++hf)
                kf[rt][hf] = *(const short8*)(kb_ +
                    (size_t)(kv0 + rt * 16 + l15) * D_ + hf * 32 + qd * 8);

        // bias bf16: per (rt,ct) 8B = 4 consecutive kv at kv0+rt*16+qd*4
        u32x2 braw[4][2];
#pragma unroll
        for (int rt = 0; rt < 4; ++rt)
#pragma unroll
            for (int ct = 0; ct < 2; ++ct)
                braw[rt][ct] = *(const u32x2*)(bb_ +
                    (size_t)(ct * 16 + l15) * N_ + kv0 + rt * 16 + qd * 4);

        // S^T = K Q^T : C row=kv(rt*16+qd*4+r), col=q(ct*16+l15)
        f32x4 St[4][2];
#pragma unroll
        for (int rt = 0; rt < 4; ++rt)
#pragma unroll
            for (int ct = 0; ct < 2; ++ct) {
                f32x4 v = (f32x4){0.f, 0.f, 0.f, 0.f};
                v = __builtin_amdgcn_mfma_f32_16x16x32_bf16(kf[rt][0], qf[ct][0], v, 0, 0, 0);
                v = __builtin_amdgcn_mfma_f32_16x16x32_bf16(kf[rt][1], qf[ct][1], v, 0, 0, 0);
                St[rt][ct] = v;
            }

        // V fragments issued early (V^T rows=dh, cols=kv)
        short8 vf[4][2];
#pragma unroll
        for (int rt = 0; rt < 4; ++rt)
#pragma unroll
            for (int hf = 0; hf < 2; ++hf)
                vf[rt][hf] = *(const short8*)(vb_ +
                    (size_t)(rt * 16 + l15) * N_ + kv0 + hf * 32 + qd * 8);

        // online softmax per q-column group ct
#pragma unroll
        for (int ct = 0; ct < 2; ++ct) {
            float sv[4][4];
            float mx = -3.0e38f;
#pragma unroll
            for (int rt = 0; rt < 4; ++rt) {
                sv[rt][0] = St[rt][ct][0] * 0.125f + lo16f(braw[rt][ct][0]);
                sv[rt][1] = St[rt][ct][1] * 0.125f + hi16f(braw[rt][ct][0]);
                sv[rt][2] = St[rt][ct][2] * 0.125f + lo16f(braw[rt][ct][1]);
                sv[rt][3] = St[rt][ct][3] * 0.125f + hi16f(braw[rt][ct][1]);
#pragma unroll
                for (int r = 0; r < 4; ++r) mx = fmaxf(mx, sv[rt][r]);
            }
            mx = fmaxf(mx, __shfl_xor(mx, 16));
            mx = fmaxf(mx, __shfl_xor(mx, 32));
            const float mnew  = fmaxf(m_i[ct], mx);
            const float alpha = __expf(m_i[ct] - mnew);
            float rsum = 0.f;
#pragma unroll
            for (int rt = 0; rt < 4; ++rt) {
                const float p0 = __expf(sv[rt][0] - mnew), p1 = __expf(sv[rt][1] - mnew);
                const float p2 = __expf(sv[rt][2] - mnew), p3 = __expf(sv[rt][3] - mnew);
                rsum += (p0 + p1) + (p2 + p3);
                u32x2 pw; pw[0] = packbf(p0, p1); pw[1] = packbf(p2, p3);
                *(u32x2*)&Pw[w][ct * 16 + l15][rt * 16 + qd * 4] = pw;
            }
            l_i[ct] = l_i[ct] * alpha + rsum;
            m_i[ct] = mnew;
#pragma unroll
            for (int rt = 0; rt < 4; ++rt)
#pragma unroll
                for (int r = 0; r < 4; ++r) Ot[rt][ct][r] *= alpha;
        }

        // P fragments (B-operand): n=q, k=kv
        short8 pf[2][2];
#pragma unroll
        for (int ct = 0; ct < 2; ++ct)
#pragma unroll
            for (int hf = 0; hf < 2; ++hf)
                pf[ct][hf] = *(const short8*)&Pw[w][ct * 16 + l15][hf * 32 + qd * 8];

        // O^T += V^T P^T
#pragma unroll
        for (int rt = 0; rt < 4; ++rt)
#pragma unroll
            for (int ct = 0; ct < 2; ++ct) {
                Ot[rt][ct] = __builtin_amdgcn_mfma_f32_16x16x32_bf16(vf[rt][0], pf[ct][0], Ot[rt][ct], 0, 0, 0);
                Ot[rt][ct] = __builtin_amdgcn_mfma_f32_16x16x32_bf16(vf[rt][1], pf[ct][1], Ot[rt][ct], 0, 0, 0);
            }
    }

    // full l per q-column within this split
#pragma unroll
    for (int ct = 0; ct < 2; ++ct) {
        l_i[ct] += __shfl_xor(l_i[ct], 16);
        l_i[ct] += __shfl_xor(l_i[ct], 32);
    }

    __syncthreads();   // all P reads done; safe to reuse smem as Obuf

    if (w >= 4) {      // split-1 waves publish m, l, O
        if (qd == 0) {
#pragma unroll
            for (int ct = 0; ct < 2; ++ct) {
                mlm[(w - 4) * 32 + ct * 16 + l15] = m_i[ct];
                mll[(w - 4) * 32 + ct * 16 + l15] = l_i[ct];
            }
        }
#pragma unroll
        for (int ct = 0; ct < 2; ++ct)
#pragma unroll
            for (int rt = 0; rt < 4; ++rt)
                *(f32x4*)&Obuf[w - 4][ct * 16 + l15][rt * 16 + qd * 4] = Ot[rt][ct];
    }
    __syncthreads();

    if (w < 4) {       // split-0 waves merge partner and store
#pragma unroll
        for (int ct = 0; ct < 2; ++ct) {
            const float mp = mlm[w * 32 + ct * 16 + l15];
            const float lp = mll[w * 32 + ct * 16 + l15];
            const float mn = fmaxf(m_i[ct], mp);
            const float fs = __expf(m_i[ct] - mn);
            const float fp = __expf(mp - mn);
            const float lt = l_i[ct] * fs + lp * fp;
            const float inv = 1.f / lt;
            const int q = q0 + ct * 16 + l15;
#pragma unroll
            for (int rt = 0; rt < 4; ++rt) {
                const f32x4 op = *(const f32x4*)&Obuf[w][ct * 16 + l15][rt * 16 + qd * 4];
                u16x4 ob;
#pragma unroll
                for (int r = 0; r < 4; ++r)
                    ob[r] = f2bf((Ot[rt][ct][r] * fs + op[r] * fp) * inv);
                *(u16x4*)(AO + (size_t)(b * N_ + q) * D_ + h * DH_ + rt * 16 + qd * 4) = ob;
            }
        }
    }
}

// ---------------------------------------------------------------------------
extern "C" void kernel_launch(void* const* d_in, const int* in_sizes, int n_in,
                              void* d_out, int out_size, void* d_ws, size_t ws_size,
                              hipStream_t stream) {
    const float* x  = (const float*)d_in[0];
    const float* ab = (const float*)d_in[1];
    const float* Wq = (const float*)d_in[2];
    const float* bq = (const float*)d_in[3];
    const float* Wk = (const float*)d_in[4];
    const float* bk = (const float*)d_in[5];
    const float* Wv = (const float*)d_in[6];
    const float* bv = (const float*)d_in[7];
    const float* Wo = (const float*)d_in[8];
    const float* bo = (const float*)d_in[9];
    const float* qg = (const float*)d_in[10];
    const float* qb = (const float*)d_in[11];
    const float* kg = (const float*)d_in[12];
    const float* kb = (const float*)d_in[13];

    // ws layout (bf16 elements)
    unsigned short* xb  = (unsigned short*)d_ws;                // [8192][512]
    unsigned short* Wb  = xb + (size_t)M_ * D_;                 // [4][512][512]
    unsigned short* Y   = Wb + (size_t)4 * D_ * D_;             // [3][8192][512]
    unsigned short* Vt  = Y  + (size_t)3 * M_ * D_;             // [4][512][2048]
    unsigned short* AO  = Vt + (size_t)M_ * D_;                 // [8192][512]
    unsigned short* bb16 = AO + (size_t)M_ * D_;                // [4][2048][2048]
    float* out = (float*)d_out;

    cvt_x<<<dim3(M_ * D_ / 1024), dim3(256), 0, stream>>>(x, xb);
    cvt_w<<<dim3(D_ * D_ / 1024, 4), dim3(256), 0, stream>>>(Wq, Wk, Wv, Wo, Wb);
    cvt_bias<<<dim3((size_t)B_ * N_ * N_ / 2048), dim3(256), 0, stream>>>(ab, bb16);

    // QKV projection with fused per-head LN on q,k
    gemm_nt<false, true><<<dim3(64, 12), dim3(256), 0, stream>>>(
        xb, Wb, bq, bk, bv, qg, qb, kg, kb, Y, nullptr);

    // V -> V^T
    transpose_v<<<dim3(32, 8, 4), dim3(256), 0, stream>>>(
        Y + (size_t)2 * M_ * D_, Vt);

    // attention
    attn6<<<dim3(2, 64, 4), dim3(512), 0, stream>>>(
        Y, Y + (size_t)M_ * D_, Vt, bb16, AO);

    // output projection -> d_out (fp32)
    gemm_nt<true, false><<<dim3(64, 4), dim3(256), 0, stream>>>(
        AO, Wb + (size_t)3 * D_ * D_, bo, bo, bo,
        nullptr, nullptr, nullptr, nullptr, nullptr, out);
}

// Round 8
// 269.623 us; speedup vs baseline: 1.3776x; 1.3776x over previous
//
#include <hip/hip_runtime.h>

typedef __attribute__((ext_vector_type(8))) short short8;
typedef __attribute__((ext_vector_type(4))) float f32x4;
typedef __attribute__((ext_vector_type(4))) int i32x4;
typedef __attribute__((ext_vector_type(4))) unsigned short u16x4;
typedef __attribute__((ext_vector_type(8))) unsigned short u16x8;
typedef __attribute__((ext_vector_type(2))) unsigned int u32x2;

#define B_  4
#define N_  2048
#define D_  512
#define H_  8
#define DH_ 64
#define M_  (B_ * N_)   // 8192

__device__ __forceinline__ float bf2f(unsigned short s) {
    union { unsigned u; float f; } un; un.u = ((unsigned)s) << 16; return un.f;
}
__device__ __forceinline__ unsigned short f2bf(float f) {
    union { float f; unsigned u; } un; un.f = f;
    unsigned r = un.u + 0x7FFFu + ((un.u >> 16) & 1u);
    return (unsigned short)(r >> 16);
}
__device__ __forceinline__ unsigned packbf(float lo, float hi) {
    union { float f; unsigned u; } a, b;
    a.f = lo; b.f = hi;
    return __builtin_amdgcn_perm(b.u + 0x8000u, a.u + 0x8000u, 0x07060302u);
}
__device__ __forceinline__ float lo16f(unsigned u) {
    union { unsigned u; float f; } un; un.u = u << 16; return un.f;
}
__device__ __forceinline__ float hi16f(unsigned u) {
    union { unsigned u; float f; } un; un.u = u & 0xFFFF0000u; return un.f;
}

typedef __attribute__((address_space(1))) const void gvoid;
typedef __attribute__((address_space(3))) void svoid;
__device__ __forceinline__ void load16_lds(const void* g, void* s) {
    __builtin_amdgcn_global_load_lds((gvoid*)g, (svoid*)s, 16, 0, 0);
}

// ---------------------------------------------------------------------------
// fp32 -> bf16 conversions
// ---------------------------------------------------------------------------
__global__ __launch_bounds__(256) void cvt_x(const float* __restrict__ src,
                                             unsigned short* __restrict__ dst) {
    const int i = (blockIdx.x * 256 + threadIdx.x) * 4;
    f32x4 v = *(const f32x4*)(src + i);
    u16x4 o;
    o[0] = f2bf(v[0]); o[1] = f2bf(v[1]); o[2] = f2bf(v[2]); o[3] = f2bf(v[3]);
    *(u16x4*)(dst + i) = o;
}

// bias fp32 [b][q][kv] -> bf16 TILED: Bt[b][q/32][kv/64][q&31][kv&63]
__global__ __launch_bounds__(256) void cvt_bias(const float* __restrict__ src,
                                                unsigned short* __restrict__ dst) {
    const size_t i = ((size_t)blockIdx.x * 256 + threadIdx.x) * 8;
    const int kv = (int)(i & 2047);
    const int q  = (int)((i >> 11) & 2047);
    const int b  = (int)(i >> 22);
    f32x4 v0 = *(const f32x4*)(src + i);
    f32x4 v1 = *(const f32x4*)(src + i + 4);
    u16x8 o;
    o[0] = f2bf(v0[0]); o[1] = f2bf(v0[1]); o[2] = f2bf(v0[2]); o[3] = f2bf(v0[3]);
    o[4] = f2bf(v1[0]); o[5] = f2bf(v1[1]); o[6] = f2bf(v1[2]); o[7] = f2bf(v1[3]);
    const size_t oi = ((((size_t)b * 64 + (q >> 5)) * 32 + (kv >> 6)) * 32 + (q & 31)) * 64 + (kv & 63);
    *(u16x8*)(dst + oi) = o;
}

__global__ __launch_bounds__(256) void cvt_w(const float* __restrict__ W0,
                                             const float* __restrict__ W1,
                                             const float* __restrict__ W2,
                                             const float* __restrict__ W3,
                                             unsigned short* __restrict__ dst) {
    const int sel = blockIdx.y;
    const float* src = (sel == 0) ? W0 : (sel == 1) ? W1 : (sel == 2) ? W2 : W3;
    unsigned short* d = dst + (size_t)sel * D_ * D_;
    const int i = (blockIdx.x * 256 + threadIdx.x) * 4;
    f32x4 v = *(const f32x4*)(src + i);
    u16x4 o;
    o[0] = f2bf(v[0]); o[1] = f2bf(v[1]); o[2] = f2bf(v[2]); o[3] = f2bf(v[3]);
    *(u16x4*)(d + i) = o;
}

// ---------------------------------------------------------------------------
// NT GEMM with global_load_lds(16B) staging + XOR-swizzled LDS.
// Tile 128x128, BK=32, 4 waves; optional fused per-head LN.
// ---------------------------------------------------------------------------
template <bool F32OUT, bool LNF>
__global__ __launch_bounds__(256, 2) void gemm_nt(
    const unsigned short* __restrict__ A,
    const unsigned short* __restrict__ W,     // [nsel][512][512]
    const float* __restrict__ Bv0,
    const float* __restrict__ Bv1,
    const float* __restrict__ Bv2,
    const float* __restrict__ g0, const float* __restrict__ be0,
    const float* __restrict__ g1, const float* __restrict__ be1,
    unsigned short* __restrict__ outb,
    float* __restrict__ outf)
{
    const int mt = blockIdx.x;
    const int nt = blockIdx.y;
    const int sel = nt >> 2;
    const unsigned short* Wp = W + (size_t)sel * D_ * D_;
    const float* Bv = (sel == 0) ? Bv0 : (sel == 1) ? Bv1 : Bv2;
    const int n0 = (nt & 3) * 128;

    __shared__ __align__(16) unsigned short As[128 * 32];
    __shared__ __align__(16) unsigned short Bs[128 * 32];

    const int tid = threadIdx.x;
    const int w   = tid >> 6;
    const int l   = tid & 63;
    const int l15 = l & 15;
    const int qd  = l >> 4;
    const int wr  = w >> 1;
    const int wc  = w & 1;

    int srow[2], scol[2];
#pragma unroll
    for (int c = 0; c < 2; ++c) {
        const int g   = (w * 2 + c) * 64 + l;
        const int row = g >> 2;
        srow[c] = row;
        scol[c] = ((g & 3) ^ (row & 3)) * 8;
    }

    f32x4 acc[4][4];
#pragma unroll
    for (int i = 0; i < 4; ++i)
#pragma unroll
        for (int j = 0; j < 4; ++j)
            acc[i][j] = (f32x4){0.f, 0.f, 0.f, 0.f};

    const int swz = qd ^ (l15 & 3);

    for (int k0 = 0; k0 < D_; k0 += 32) {
        __syncthreads();
#pragma unroll
        for (int c = 0; c < 2; ++c) {
            load16_lds(A  + (size_t)(mt * 128 + srow[c]) * D_ + k0 + scol[c],
                       As + (w * 2 + c) * 512);
            load16_lds(Wp + (size_t)(n0 + srow[c]) * D_ + k0 + scol[c],
                       Bs + (w * 2 + c) * 512);
        }
        __syncthreads();

        short8 af[4], bfr[4];
#pragma unroll
        for (int rt = 0; rt < 4; ++rt)
            af[rt] = *(const short8*)&As[(wr * 64 + rt * 16 + l15) * 32 + swz * 8];
#pragma unroll
        for (int ct = 0; ct < 4; ++ct)
            bfr[ct] = *(const short8*)&Bs[(wc * 64 + ct * 16 + l15) * 32 + swz * 8];
#pragma unroll
        for (int rt = 0; rt < 4; ++rt)
#pragma unroll
            for (int ct = 0; ct < 4; ++ct)
                acc[rt][ct] = __builtin_amdgcn_mfma_f32_16x16x32_bf16(
                    af[rt], bfr[ct], acc[rt][ct], 0, 0, 0);
    }

    const float* gam = (sel == 0) ? g0 : g1;
    const float* bet = (sel == 0) ? be0 : be1;
    float gv[4], bv2[4];
    if (LNF) {
#pragma unroll
        for (int ct = 0; ct < 4; ++ct) { gv[ct] = gam[ct * 16 + l15]; bv2[ct] = bet[ct * 16 + l15]; }
    }

#pragma unroll
    for (int rt = 0; rt < 4; ++rt) {
        float v[4][4];
#pragma unroll
        for (int ct = 0; ct < 4; ++ct) {
            const float bias = Bv[n0 + wc * 64 + ct * 16 + l15];
#pragma unroll
            for (int r = 0; r < 4; ++r) v[ct][r] = acc[rt][ct][r] + bias;
        }
        if (LNF && sel < 2) {
#pragma unroll
            for (int r = 0; r < 4; ++r) {
                float s  = v[0][r] + v[1][r] + v[2][r] + v[3][r];
                float s2 = v[0][r]*v[0][r] + v[1][r]*v[1][r] + v[2][r]*v[2][r] + v[3][r]*v[3][r];
#pragma unroll
                for (int o = 1; o <= 8; o <<= 1) {
                    s  += __shfl_xor(s, o);
                    s2 += __shfl_xor(s2, o);
                }
                const float mu  = s * 0.015625f;
                const float var = s2 * 0.015625f - mu * mu;
                const float rs  = rsqrtf(var + 1e-6f);
#pragma unroll
                for (int ct = 0; ct < 4; ++ct)
                    v[ct][r] = (v[ct][r] - mu) * rs * gv[ct] + bv2[ct];
            }
        }
#pragma unroll
        for (int ct = 0; ct < 4; ++ct) {
            const int col  = n0 + wc * 64 + ct * 16 + l15;
            const int row0 = mt * 128 + wr * 64 + rt * 16 + qd * 4;
#pragma unroll
            for (int r = 0; r < 4; ++r) {
                const size_t oidx = (size_t)(row0 + r) * D_ + col;
                if (F32OUT) outf[oidx] = v[ct][r];
                else        outb[(size_t)sel * M_ * D_ + oidx] = f2bf(v[ct][r]);
            }
        }
    }
}

// ---------------------------------------------------------------------------
// pack_kv: K[b*N+n][512] -> Kt[b][h][nt][kv64][dh64] (8KB contiguous tiles)
//          V[b*N+n][512] -> Vt2[b][h][nt][dh64][kv64] (transposed tiles)
// ---------------------------------------------------------------------------
__global__ __launch_bounds__(256) void pack_kv(
    const unsigned short* __restrict__ K, const unsigned short* __restrict__ V,
    unsigned short* __restrict__ Kt, unsigned short* __restrict__ Vt2)
{
    const int nt = blockIdx.x, b = blockIdx.y;
    const int tid = threadIdx.x;
    __shared__ __align__(16) unsigned short Vl[64][520];

#pragma unroll
    for (int i = 0; i < 16; ++i) {
        const int c = i * 256 + tid;         // 0..4095
        const int row = c >> 6, ch = c & 63;
        const size_t srow = ((size_t)(b * N_ + nt * 64 + row)) * D_ + ch * 8;
        i32x4 kd = *(const i32x4*)(K + srow);
        const int h = ch >> 3, dc = ch & 7;
        *(i32x4*)(Kt + ((((size_t)(b * 8 + h) * 32 + nt) * 64 + row) * 64) + dc * 8) = kd;
        i32x4 vd = *(const i32x4*)(V + srow);
        *(i32x4*)&Vl[row][ch * 8] = vd;
    }
    __syncthreads();
#pragma unroll
    for (int i = 0; i < 16; ++i) {
        const int c = i * 256 + tid;
        const int h = c >> 9, r = c & 511;
        const int dh = r >> 3, kc = r & 7;
        u16x8 o;
#pragma unroll
        for (int j = 0; j < 8; ++j) o[j] = Vl[kc * 8 + j][h * 64 + dh];
        *(u16x8*)(Vt2 + ((((size_t)(b * 8 + h) * 32 + nt) * 64 + dh) * 64) + kc * 8) = o;
    }
}

// ---------------------------------------------------------------------------
// attn7: block = 4 waves x 32 q-rows (128 q total), one (b,h). kv loop over
// 32 tiles of 64. K/V tiles staged COALESCED into shared LDS via
// global_load_lds from pre-packed contiguous tiles; bias staged per-wave from
// tiled layout. Fragments read from XOR-swizzled LDS. 2 barriers/iter.
// ---------------------------------------------------------------------------
__global__ __launch_bounds__(256, 3) void attn7(
    const unsigned short* __restrict__ Qm,
    const unsigned short* __restrict__ Kt,
    const unsigned short* __restrict__ Vt2,
    const unsigned short* __restrict__ Bt,
    unsigned short* __restrict__ AO)
{
    const int qt = blockIdx.x;   // 0..15  (128 q-rows each)
    const int h  = blockIdx.y;   // 0..7
    const int b  = blockIdx.z;   // 0..3
    const int w  = threadIdx.x >> 6;
    const int l  = threadIdx.x & 63;
    const int l15 = l & 15;
    const int qd  = l >> 4;
    const int q0 = qt * 128 + w * 32;

    // LDS: Kbuf 8KB | Vbuf 8KB | bias 4x4KB | Pw 4x32x72x2B = 51200 B
    __shared__ __align__(16) unsigned char smem[51200];
    unsigned char* Kb = smem;
    unsigned char* Vb = smem + 8192;
    unsigned char* Bb = smem + 16384 + w * 4096;
    unsigned short* PwB = (unsigned short*)(smem + 32768) + w * 32 * 72;

    // Q fragments (B-operand): n=q(ct*16+l15), k=dh(hf*32+qd*8+j)
    short8 qf[2][2];
#pragma unroll
    for (int ct = 0; ct < 2; ++ct)
#pragma unroll
        for (int hf = 0; hf < 2; ++hf)
            qf[ct][hf] = *(const short8*)(Qm +
                (size_t)(b * N_ + q0 + ct * 16 + l15) * D_ + h * DH_ + hf * 32 + qd * 8);

    f32x4 Ot[4][2];
#pragma unroll
    for (int rt = 0; rt < 4; ++rt)
#pragma unroll
        for (int ct = 0; ct < 2; ++ct) Ot[rt][ct] = (f32x4){0.f, 0.f, 0.f, 0.f};
    float m_i[2] = {-3.0e38f, -3.0e38f};
    float l_i[2] = {0.f, 0.f};   // lane-partial

    const unsigned short* Ktile0 = Kt  + (((size_t)(b * 8 + h) * 32) * 64) * 64;
    const unsigned short* Vtile0 = Vt2 + (((size_t)(b * 8 + h) * 32) * 64) * 64;
    const unsigned short* Btile0 = Bt  + (((size_t)b * 64 + qt * 4 + w) * 32) * 2048;

    for (int kt = 0; kt < 32; ++kt) {
        const unsigned short* Ktile = Ktile0 + (size_t)kt * 4096;
        const unsigned short* Vtile = Vtile0 + (size_t)kt * 4096;
        const unsigned short* Btile = Btile0 + (size_t)kt * 2048;

        __syncthreads();   // previous iter's LDS reads complete
        // stage K,V (shared; 2 instrs each per wave; coalesced 128B groups)
#pragma unroll
        for (int i = 0; i < 2; ++i) {
            const int c = (w * 2 + i) * 64 + l;     // 0..511
            const int row = c >> 3, g = c & 7;
            const int sg = g ^ (row & 7);
            load16_lds(Ktile + row * 64 + sg * 8, Kb + c * 16);
            load16_lds(Vtile + row * 64 + sg * 8, Vb + c * 16);
        }
        // stage own bias tile (4KB, 4 instrs)
#pragma unroll
        for (int i = 0; i < 4; ++i) {
            const int c = i * 64 + l;               // 0..255
            const int q = c >> 3, g = c & 7;
            const int sg = g ^ (q & 7);
            load16_lds(Btile + q * 64 + sg * 8, Bb + c * 16);
        }
        __syncthreads();   // staging visible

        // K fragments from LDS (A-operand): m=kv(rt*16+l15), k=dh
        short8 kf[4][2];
#pragma unroll
        for (int rt = 0; rt < 4; ++rt) {
            const int kv = rt * 16 + l15;
#pragma unroll
            for (int hf = 0; hf < 2; ++hf) {
                const int cidx = (hf * 4 + qd) ^ (kv & 7);
                kf[rt][hf] = *(const short8*)(Kb + kv * 128 + cidx * 16);
            }
        }

        // S^T = K Q^T
        f32x4 St[4][2];
#pragma unroll
        for (int rt = 0; rt < 4; ++rt)
#pragma unroll
            for (int ct = 0; ct < 2; ++ct) {
                f32x4 v = (f32x4){0.f, 0.f, 0.f, 0.f};
                v = __builtin_amdgcn_mfma_f32_16x16x32_bf16(kf[rt][0], qf[ct][0], v, 0, 0, 0);
                v = __builtin_amdgcn_mfma_f32_16x16x32_bf16(kf[rt][1], qf[ct][1], v, 0, 0, 0);
                St[rt][ct] = v;
            }

        // bias from LDS: q=ct*16+l15, kv granule rt*4+qd (8B)
        u32x2 braw[4][2];
#pragma unroll
        for (int rt = 0; rt < 4; ++rt)
#pragma unroll
            for (int ct = 0; ct < 2; ++ct) {
                const int q = ct * 16 + l15;
                const int cidx = (rt * 2 + (qd >> 1)) ^ (q & 7);
                braw[rt][ct] = *(const u32x2*)(Bb + q * 128 + cidx * 16 + (qd & 1) * 8);
            }

        // V fragments (A-operand): m=dh(rt*16+l15), k=kv
        short8 vf[4][2];
#pragma unroll
        for (int rt = 0; rt < 4; ++rt) {
            const int dh = rt * 16 + l15;
#pragma unroll
            for (int hf = 0; hf < 2; ++hf) {
                const int cidx = (hf * 4 + qd) ^ (dh & 7);
                vf[rt][hf] = *(const short8*)(Vb + dh * 128 + cidx * 16);
            }
        }

        // online softmax per q-column group ct
#pragma unroll
        for (int ct = 0; ct < 2; ++ct) {
            float sv[4][4];
            float mx = -3.0e38f;
#pragma unroll
            for (int rt = 0; rt < 4; ++rt) {
                sv[rt][0] = St[rt][ct][0] * 0.125f + lo16f(braw[rt][ct][0]);
                sv[rt][1] = St[rt][ct][1] * 0.125f + hi16f(braw[rt][ct][0]);
                sv[rt][2] = St[rt][ct][2] * 0.125f + lo16f(braw[rt][ct][1]);
                sv[rt][3] = St[rt][ct][3] * 0.125f + hi16f(braw[rt][ct][1]);
#pragma unroll
                for (int r = 0; r < 4; ++r) mx = fmaxf(mx, sv[rt][r]);
            }
            mx = fmaxf(mx, __shfl_xor(mx, 16));
            mx = fmaxf(mx, __shfl_xor(mx, 32));
            const float mnew  = fmaxf(m_i[ct], mx);
            const float alpha = __expf(m_i[ct] - mnew);
            float rsum = 0.f;
#pragma unroll
            for (int rt = 0; rt < 4; ++rt) {
                const float p0 = __expf(sv[rt][0] - mnew), p1 = __expf(sv[rt][1] - mnew);
                const float p2 = __expf(sv[rt][2] - mnew), p3 = __expf(sv[rt][3] - mnew);
                rsum += (p0 + p1) + (p2 + p3);
                u32x2 pw; pw[0] = packbf(p0, p1); pw[1] = packbf(p2, p3);
                *(u32x2*)&PwB[(ct * 16 + l15) * 72 + rt * 16 + qd * 4] = pw;
            }
            l_i[ct] = l_i[ct] * alpha + rsum;
            m_i[ct] = mnew;
#pragma unroll
            for (int rt = 0; rt < 4; ++rt)
#pragma unroll
                for (int r = 0; r < 4; ++r) Ot[rt][ct][r] *= alpha;
        }

        // P fragments (B-operand): n=q, k=kv
        short8 pf[2][2];
#pragma unroll
        for (int ct = 0; ct < 2; ++ct)
#pragma unroll
            for (int hf = 0; hf < 2; ++hf)
                pf[ct][hf] = *(const short8*)&PwB[(ct * 16 + l15) * 72 + hf * 32 + qd * 8];

        // O^T += V^T P^T
#pragma unroll
        for (int rt = 0; rt < 4; ++rt)
#pragma unroll
            for (int ct = 0; ct < 2; ++ct) {
                Ot[rt][ct] = __builtin_amdgcn_mfma_f32_16x16x32_bf16(vf[rt][0], pf[ct][0], Ot[rt][ct], 0, 0, 0);
                Ot[rt][ct] = __builtin_amdgcn_mfma_f32_16x16x32_bf16(vf[rt][1], pf[ct][1], Ot[rt][ct], 0, 0, 0);
            }
    }

    // epilogue
#pragma unroll
    for (int ct = 0; ct < 2; ++ct) {
        l_i[ct] += __shfl_xor(l_i[ct], 16);
        l_i[ct] += __shfl_xor(l_i[ct], 32);
        const float inv = 1.f / l_i[ct];
        const int q = q0 + ct * 16 + l15;
#pragma unroll
        for (int rt = 0; rt < 4; ++rt) {
            u16x4 ob;
#pragma unroll
            for (int r = 0; r < 4; ++r) ob[r] = f2bf(Ot[rt][ct][r] * inv);
            *(u16x4*)(AO + (size_t)(b * N_ + q) * D_ + h * DH_ + rt * 16 + qd * 4) = ob;
        }
    }
}

// ---------------------------------------------------------------------------
extern "C" void kernel_launch(void* const* d_in, const int* in_sizes, int n_in,
                              void* d_out, int out_size, void* d_ws, size_t ws_size,
                              hipStream_t stream) {
    const float* x  = (const float*)d_in[0];
    const float* ab = (const float*)d_in[1];
    const float* Wq = (const float*)d_in[2];
    const float* bq = (const float*)d_in[3];
    const float* Wk = (const float*)d_in[4];
    const float* bk = (const float*)d_in[5];
    const float* Wv = (const float*)d_in[6];
    const float* bv = (const float*)d_in[7];
    const float* Wo = (const float*)d_in[8];
    const float* bo = (const float*)d_in[9];
    const float* qg = (const float*)d_in[10];
    const float* qb = (const float*)d_in[11];
    const float* kg = (const float*)d_in[12];
    const float* kb = (const float*)d_in[13];

    // ws layout (bf16 elements)
    unsigned short* xb  = (unsigned short*)d_ws;                // [8192][512]
    unsigned short* Wb  = xb  + (size_t)M_ * D_;                // [4][512][512]
    unsigned short* Y   = Wb  + (size_t)4 * D_ * D_;            // [3][8192][512]
    unsigned short* Kt  = Y   + (size_t)3 * M_ * D_;            // [4][8][32][64][64]
    unsigned short* Vt2 = Kt  + (size_t)M_ * D_;                // [4][8][32][64][64]
    unsigned short* AO  = Vt2 + (size_t)M_ * D_;                // [8192][512]
    unsigned short* Bt  = AO  + (size_t)M_ * D_;                // [4][64][32][32][64]
    float* out = (float*)d_out;

    cvt_x<<<dim3(M_ * D_ / 1024), dim3(256), 0, stream>>>(x, xb);
    cvt_w<<<dim3(D_ * D_ / 1024, 4), dim3(256), 0, stream>>>(Wq, Wk, Wv, Wo, Wb);
    cvt_bias<<<dim3((int)((size_t)B_ * N_ * N_ / 2048)), dim3(256), 0, stream>>>(ab, Bt);

    // QKV projection with fused per-head LN on q,k
    gemm_nt<false, true><<<dim3(64, 12), dim3(256), 0, stream>>>(
        xb, Wb, bq, bk, bv, qg, qb, kg, kb, Y, nullptr);

    // pack K,V into contiguous per-head tiles (V transposed)
    pack_kv<<<dim3(32, 4), dim3(256), 0, stream>>>(
        Y + (size_t)M_ * D_, Y + (size_t)2 * M_ * D_, Kt, Vt2);

    // attention
    attn7<<<dim3(16, 8, 4), dim3(256), 0, stream>>>(
        Y, Kt, Vt2, Bt, AO);

    // output projection -> d_out (fp32)
    gemm_nt<true, false><<<dim3(64, 4), dim3(256), 0, stream>>>(
        AO, Wb + (size_t)3 * D_ * D_, bo, bo, bo,
        nullptr, nullptr, nullptr, nullptr, nullptr, out);
}